// Round 3
// baseline (137.986 us; speedup 1.0000x reference)
//
#include <hip/hip_runtime.h>
#include <hip/hip_fp16.h>

typedef _Float16 f16;
typedef _Float16 f16x8 __attribute__((ext_vector_type(8)));
typedef float f32x4 __attribute__((ext_vector_type(4)));

#define AS1(p) ((const __attribute__((address_space(1))) void*)(p))
#define AS3(p) ((__attribute__((address_space(3))) void*)(p))

__device__ __forceinline__ void gload16(const void* g, void* l) {
  __builtin_amdgcn_global_load_lds(AS1(g), AS3(l), 16, 0, 0);
}

// ---------------------------------------------------------------------------
// Generic tiled transpose + f32->f16 convert.
// in: (R x C) rows r stride in_rs, batch stride in_bs (element units)
// out: (C x R) rows c stride out_rs, batch stride out_bs
// grid: (C/64, R/64, batch), 256 threads. All dims multiples of 64.
// ---------------------------------------------------------------------------
__global__ __launch_bounds__(256) void tkern(const float* __restrict__ in,
                                             f16* __restrict__ out,
                                             long in_rs, long in_bs,
                                             long out_rs, long out_bs) {
  __shared__ float t[64][68];
  const float* ip = in + blockIdx.z * in_bs + (long)(blockIdx.y * 64) * in_rs + blockIdx.x * 64;
  f16* op = out + blockIdx.z * out_bs + (long)(blockIdx.x * 64) * out_rs + blockIdx.y * 64;
  int tid = threadIdx.x;
  {
    int c4 = (tid & 15) * 4, r0 = tid >> 4;
#pragma unroll
    for (int p = 0; p < 4; ++p) {
      int r = r0 + 16 * p;
      float4 v = *(const float4*)(ip + (long)r * in_rs + c4);
      t[c4 + 0][r] = v.x; t[c4 + 1][r] = v.y; t[c4 + 2][r] = v.z; t[c4 + 3][r] = v.w;
    }
  }
  __syncthreads();
  {
    int r4 = (tid & 15) * 4, c0 = tid >> 4;
#pragma unroll
    for (int p = 0; p < 4; ++p) {
      int c = c0 + 16 * p;
      float4 v = *(const float4*)(&t[c][r4]);
      union { f16 h[4]; unsigned long long u; } pk;
      pk.h[0] = (f16)v.x; pk.h[1] = (f16)v.y; pk.h[2] = (f16)v.z; pk.h[3] = (f16)v.w;
      *(unsigned long long*)(op + (long)c * out_rs + r4) = pk.u;
    }
  }
}

// ---------------------------------------------------------------------------
// QKV projection: D = A(4096x256) * B(2048x256)^T, both f16 k-contiguous.
// z=0: Q (A=Xq,B=Wqt) -> Qh[b][h][s][fi]
// z=1: K (A=Xkv,B=Wkt) -> Kh[b][h][s][fi]
// z=2: V (A=Xkv,B=Wvt) -> Vt[b][h][fi][s]   (transposed for PV step)
// grid (32,16,3), 256 threads, BM=BN=128, BK=64.
// ---------------------------------------------------------------------------
__global__ __launch_bounds__(256) void projk(
    const f16* __restrict__ Xq, const f16* __restrict__ Xkv,
    const f16* __restrict__ Wqt, const f16* __restrict__ Wkt, const f16* __restrict__ Wvt,
    f16* __restrict__ Qh, f16* __restrict__ Kh, f16* __restrict__ Vt) {
  __shared__ char sm[34816];  // 32KB staging, 34KB bounce (union use)
  int z = blockIdx.z;
  const f16* A = (z == 0) ? Xq : Xkv;
  const f16* B = (z == 0) ? Wqt : (z == 1) ? Wkt : Wvt;
  int m0 = blockIdx.x * 128, n0 = blockIdx.y * 128;
  int tid = threadIdx.x, wave = tid >> 6, lane = tid & 63;
  int wm = wave & 1, wn = wave >> 1;
  char* As = sm;
  char* Bs = sm + 16384;
  f32x4 acc[4][4];
#pragma unroll
  for (int i = 0; i < 4; ++i)
#pragma unroll
    for (int j = 0; j < 4; ++j) acc[i][j] = (f32x4){0.f, 0.f, 0.f, 0.f};

  for (int kt = 0; kt < 4; ++kt) {
    int k0 = kt * 64;
    __syncthreads();
#pragma unroll
    for (int is = 0; is < 4; ++is) {
      int loff = is * 4096 + wave * 1024;
      int g = loff + lane * 16;
      int row = g >> 7, sl = (g >> 4) & 7;
      int sp = (sl ^ (row & 7)) * 8;
      gload16(A + (long)(m0 + row) * 256 + k0 + sp, As + loff);
      gload16(B + (long)(n0 + row) * 256 + k0 + sp, Bs + loff);
    }
    __syncthreads();
#pragma unroll
    for (int t = 0; t < 2; ++t) {
      f16x8 af[4], bf[4];
#pragma unroll
      for (int mi = 0; mi < 4; ++mi) {
        int row = wm * 64 + mi * 16 + (lane & 15);
        int sl = (t * 4 + (lane >> 4)) ^ (row & 7);
        af[mi] = *(const f16x8*)(As + row * 128 + sl * 16);
      }
#pragma unroll
      for (int ni = 0; ni < 4; ++ni) {
        int row = wn * 64 + ni * 16 + (lane & 15);
        int sl = (t * 4 + (lane >> 4)) ^ (row & 7);
        bf[ni] = *(const f16x8*)(Bs + row * 128 + sl * 16);
      }
#pragma unroll
      for (int mi = 0; mi < 4; ++mi)
#pragma unroll
        for (int ni = 0; ni < 4; ++ni)
          acc[mi][ni] = __builtin_amdgcn_mfma_f32_16x16x32_f16(af[mi], bf[ni], acc[mi][ni], 0, 0, 0);
    }
  }
  __syncthreads();
  // bounce tile into LDS as L[cc][rs], row stride 272B (16B-aligned, conflict-light)
#pragma unroll
  for (int mi = 0; mi < 4; ++mi)
#pragma unroll
    for (int ni = 0; ni < 4; ++ni) {
      int cc = wn * 64 + ni * 16 + (lane & 15);
      int rs0 = wm * 64 + mi * 16 + (lane >> 4) * 4;
      union { f16 h[4]; unsigned long long u; } pk;
#pragma unroll
      for (int r = 0; r < 4; ++r) pk.h[r] = (f16)acc[mi][ni][r];
      *(unsigned long long*)(sm + cc * 272 + rs0 * 2) = pk.u;
    }
  __syncthreads();
  if (z < 2) {
    f16* outp = (z == 0) ? Qh : Kh;
#pragma unroll
    for (int pass = 0; pass < 4; ++pass) {
      int item = pass * 256 + tid;
      int rs = item & 127, h = item >> 7;
      int m = m0 + rs, b = m >> 10, s = m & 1023;
      union { unsigned short u16[16]; uint4 q[2]; } pk;
#pragma unroll
      for (int u = 0; u < 16; ++u)
        pk.u16[u] = *(const unsigned short*)(sm + (h + 8 * u) * 272 + rs * 2);
      f16* dst = outp + ((long)(b * 8 + h) * 1024 + s) * 256 + (n0 >> 3);
      *(uint4*)dst = pk.q[0];
      *(uint4*)(dst + 8) = pk.q[1];
    }
  } else {
    int cc = tid >> 1, half = tid & 1;
    int c = n0 + cc, h = c & 7, fi = c >> 3;
    int m = m0 + half * 64;
    int b = m >> 10, s0 = m & 1023;
    uint4 q[8];
#pragma unroll
    for (int j = 0; j < 8; ++j)
      q[j] = *(const uint4*)(sm + cc * 272 + half * 128 + j * 16);
    f16* dst = Vt + ((long)(b * 8 + h) * 256 + fi) * 1024 + s0;
#pragma unroll
    for (int j = 0; j < 8; ++j) *(uint4*)(dst + j * 8) = q[j];
  }
}

// ---------------------------------------------------------------------------
// Fused attention: per block one (bh, 64-row i-tile). Q in regs; stream
// 32-wide K/V j-tiles through swizzled LDS; sigmoid(16*s); P via LDS;
// PV accumulates 64x256 f32. Writes Zb[b][h][s][fi] f16.
// Zb may alias Qh: each block reads only its own (bh,i-tile) Q rows into
// registers up front, then writes exactly those addresses at the end.
// grid 512 (XCD-swizzled), 256 threads.
// ---------------------------------------------------------------------------
__global__ __launch_bounds__(256) void attnk(
    const f16* __restrict__ Qh, const f16* __restrict__ Kh,
    const f16* __restrict__ Vt, f16* __restrict__ Zb) {
  __shared__ char sm[36864];
  char* Ks = sm;           // [32][512B]
  char* Vs = sm + 16384;   // [256][64B]
  char* Ps = sm + 32768;   // [64][64B]
  int flat = blockIdx.x;
  int xcd = flat & 7, slotb = flat >> 3;
  int bh = xcd + 8 * (slotb & 3);   // 4 heads per XCD -> K/V fit 4MB L2
  int i0 = (slotb >> 2) * 64;
  int tid = threadIdx.x, wave = tid >> 6, lane = tid & 63;
  const f16* Qp = Qh + (long)bh * 262144;
  const f16* Kp = Kh + (long)bh * 262144;
  const f16* Vp = Vt + (long)bh * 262144;
  f16x8 q[8];
  {
    const f16* qr = Qp + (long)(i0 + wave * 16 + (lane & 15)) * 256 + (lane >> 4) * 8;
#pragma unroll
    for (int t = 0; t < 8; ++t) q[t] = *(const f16x8*)(qr + t * 32);
  }
  f32x4 acc[4][4];
#pragma unroll
  for (int i = 0; i < 4; ++i)
#pragma unroll
    for (int j = 0; j < 4; ++j) acc[i][j] = (f32x4){0.f, 0.f, 0.f, 0.f};

  for (int jt = 0; jt < 32; ++jt) {
    int j0 = jt * 32;
    __syncthreads();
#pragma unroll
    for (int is = 0; is < 4; ++is) {
      int loff = is * 4096 + wave * 1024;
      int g = loff + lane * 16;
      {
        int row = g >> 9, sl = (g >> 4) & 31;
        gload16(Kp + (long)(j0 + row) * 256 + ((sl ^ (row & 7)) * 8), Ks + loff);
      }
      {
        int row = g >> 6, sl = (g >> 4) & 3;
        gload16(Vp + (long)row * 1024 + j0 + ((sl ^ ((row >> 1) & 3)) * 8), Vs + loff);
      }
    }
    __syncthreads();
    f32x4 accs[2];
    accs[0] = (f32x4){0.f, 0.f, 0.f, 0.f};
    accs[1] = (f32x4){0.f, 0.f, 0.f, 0.f};
#pragma unroll
    for (int t = 0; t < 8; ++t) {
#pragma unroll
      for (int jf = 0; jf < 2; ++jf) {
        int jr = jf * 16 + (lane & 15);
        int sl = (t * 4 + (lane >> 4)) ^ (jr & 7);
        f16x8 kf = *(const f16x8*)(Ks + jr * 512 + sl * 16);
        accs[jf] = __builtin_amdgcn_mfma_f32_16x16x32_f16(q[t], kf, accs[jf], 0, 0, 0);
      }
    }
    // sigmoid(16*x) = 1/(1+2^(-16*log2e*x)); write P to swizzled LDS
#pragma unroll
    for (int jf = 0; jf < 2; ++jf) {
      int j = jf * 16 + (lane & 15);
#pragma unroll
      for (int r = 0; r < 4; ++r) {
        int i = wave * 16 + (lane >> 4) * 4 + r;
        float x = accs[jf][r];
        float p = __builtin_amdgcn_rcpf(1.0f + __builtin_amdgcn_exp2f(x * -23.083120654223414f));
        *(f16*)(Ps + i * 64 + ((j * 2) ^ (((i >> 1) & 3) << 4))) = (f16)p;
      }
    }
    __syncthreads();
    f16x8 pa[4];
#pragma unroll
    for (int mi = 0; mi < 4; ++mi) {
      int ir = mi * 16 + (lane & 15);
      int sl = (lane >> 4) ^ ((ir >> 1) & 3);
      pa[mi] = *(const f16x8*)(Ps + ir * 64 + sl * 16);
    }
#pragma unroll
    for (int nf = 0; nf < 4; ++nf) {
      int fr = wave * 64 + nf * 16 + (lane & 15);
      int sl = (lane >> 4) ^ ((fr >> 1) & 3);
      f16x8 vb = *(const f16x8*)(Vs + fr * 64 + sl * 16);
#pragma unroll
      for (int mi = 0; mi < 4; ++mi)
        acc[mi][nf] = __builtin_amdgcn_mfma_f32_16x16x32_f16(pa[mi], vb, acc[mi][nf], 0, 0, 0);
    }
  }
  f16* zp = Zb + ((long)bh * 1024 + i0) * 256;
#pragma unroll
  for (int mi = 0; mi < 4; ++mi)
#pragma unroll
    for (int nf = 0; nf < 4; ++nf)
#pragma unroll
      for (int r = 0; r < 4; ++r) {
        int i = mi * 16 + (lane >> 4) * 4 + r;
        int f = wave * 64 + nf * 16 + (lane & 15);
        zp[(long)i * 256 + f] = (f16)acc[mi][nf][r];
      }
}

// ---------------------------------------------------------------------------
// Output projection + ReLU: out[b][fo][s] = relu(sum_k' Wzt[fo][k'] * Zb[...])
// k' = h*256+fi so each 64-chunk is contiguous in Zb[b][h][s][fi].
// grid (4,16,4), 256 threads, BM=BN=BK=64.
// ---------------------------------------------------------------------------
__global__ __launch_bounds__(256) void zkern(
    const f16* __restrict__ Wzt, const f16* __restrict__ Zb,
    float* __restrict__ out) {
  __shared__ char sm[16384];
  char* As = sm;
  char* Bs = sm + 8192;
  int fo0 = blockIdx.x * 64, s0 = blockIdx.y * 64, b = blockIdx.z;
  int tid = threadIdx.x, wave = tid >> 6, lane = tid & 63;
  int wm = wave & 1, wn = wave >> 1;
  f32x4 acc[2][2];
#pragma unroll
  for (int i = 0; i < 2; ++i)
#pragma unroll
    for (int j = 0; j < 2; ++j) acc[i][j] = (f32x4){0.f, 0.f, 0.f, 0.f};

  for (int kt = 0; kt < 32; ++kt) {
    int k0 = kt * 64, h = k0 >> 8, fi0 = k0 & 255;
    __syncthreads();
#pragma unroll
    for (int is = 0; is < 2; ++is) {
      int loff = is * 4096 + wave * 1024;
      int g = loff + lane * 16;
      int row = g >> 7, sl = (g >> 4) & 7;
      int sp = (sl ^ (row & 7)) * 8;
      gload16(Wzt + (long)(fo0 + row) * 2048 + k0 + sp, As + loff);
      gload16(Zb + ((long)(b * 8 + h) * 1024 + s0 + row) * 256 + fi0 + sp, Bs + loff);
    }
    __syncthreads();
#pragma unroll
    for (int t = 0; t < 2; ++t) {
      f16x8 af[2], bf[2];
#pragma unroll
      for (int mi = 0; mi < 2; ++mi) {
        int row = wm * 32 + mi * 16 + (lane & 15);
        int sl = (t * 4 + (lane >> 4)) ^ (row & 7);
        af[mi] = *(const f16x8*)(As + row * 128 + sl * 16);
      }
#pragma unroll
      for (int ni = 0; ni < 2; ++ni) {
        int row = wn * 32 + ni * 16 + (lane & 15);
        int sl = (t * 4 + (lane >> 4)) ^ (row & 7);
        bf[ni] = *(const f16x8*)(Bs + row * 128 + sl * 16);
      }
#pragma unroll
      for (int mi = 0; mi < 2; ++mi)
#pragma unroll
        for (int ni = 0; ni < 2; ++ni)
          acc[mi][ni] = __builtin_amdgcn_mfma_f32_16x16x32_f16(af[mi], bf[ni], acc[mi][ni], 0, 0, 0);
    }
  }
#pragma unroll
  for (int mi = 0; mi < 2; ++mi)
#pragma unroll
    for (int ni = 0; ni < 2; ++ni)
#pragma unroll
      for (int r = 0; r < 4; ++r) {
        int fo = fo0 + wm * 32 + mi * 16 + (lane >> 4) * 4 + r;
        int s = s0 + wn * 32 + ni * 16 + (lane & 15);
        float v = acc[mi][ni][r];
        out[((long)b * 256 + fo) * 1024 + s] = v > 0.f ? v : 0.f;
      }
}

extern "C" void kernel_launch(void* const* d_in, const int* in_sizes, int n_in,
                              void* d_out, int out_size, void* d_ws, size_t ws_size,
                              hipStream_t stream) {
  const float* qin = (const float*)d_in[0];
  const float* kvin = (const float*)d_in[1];
  const float* Wq = (const float*)d_in[2];
  const float* Wk = (const float*)d_in[3];
  const float* Wv = (const float*)d_in[4];
  const float* Wz = (const float*)d_in[5];
  float* out = (float*)d_out;
  char* ws = (char*)d_ws;
  const long MB = 1 << 20;
  f16* Xq  = (f16*)(ws + 0 * MB);   // [b][s][f]      2MB
  f16* Xkv = (f16*)(ws + 2 * MB);   // [b][s][f]      2MB
  f16* Wqt = (f16*)(ws + 4 * MB);   // [c][f]         1MB
  f16* Wkt = (f16*)(ws + 5 * MB);
  f16* Wvt = (f16*)(ws + 6 * MB);
  f16* Wzt = (f16*)(ws + 7 * MB);   // [fo][h*256+fi] 1MB
  f16* Qh  = (f16*)(ws + 8 * MB);   // [b][h][s][fi] 16MB  (aliased by Zb)
  f16* Kh  = (f16*)(ws + 24 * MB);  // [b][h][s][fi] 16MB
  f16* Vt  = (f16*)(ws + 40 * MB);  // [b][h][fi][s] 16MB
  f16* Zb  = Qh;                    // alias: attnk reads Q rows before writing Z rows
  dim3 blk(256);
  tkern<<<dim3(16, 4, 4), blk, 0, stream>>>(qin, Xq, 1024L, 262144L, 256L, 262144L);
  tkern<<<dim3(16, 4, 4), blk, 0, stream>>>(kvin, Xkv, 1024L, 262144L, 256L, 262144L);
  tkern<<<dim3(32, 4, 1), blk, 0, stream>>>(Wq, Wqt, 2048L, 0L, 256L, 0L);
  tkern<<<dim3(32, 4, 1), blk, 0, stream>>>(Wk, Wkt, 2048L, 0L, 256L, 0L);
  tkern<<<dim3(32, 4, 1), blk, 0, stream>>>(Wv, Wvt, 2048L, 0L, 256L, 0L);
  tkern<<<dim3(4, 4, 8),  blk, 0, stream>>>(Wz, Wzt, 2048L, 256L, 2048L, 256L);
  projk<<<dim3(32, 16, 3), blk, 0, stream>>>(Xq, Xkv, Wqt, Wkt, Wvt, Qh, Kh, Vt);
  attnk<<<dim3(512), blk, 0, stream>>>(Qh, Kh, Vt, Zb);
  zkern<<<dim3(4, 16, 4), blk, 0, stream>>>(Wzt, Zb, out);
}

// Round 4
// 126.330 us; speedup vs baseline: 1.0923x; 1.0923x over previous
//
#include <hip/hip_runtime.h>
#include <hip/hip_fp16.h>

typedef _Float16 f16;
typedef _Float16 f16x8 __attribute__((ext_vector_type(8)));
typedef float f32x4 __attribute__((ext_vector_type(4)));

#define AS1(p) ((const __attribute__((address_space(1))) void*)(p))
#define AS3(p) ((__attribute__((address_space(3))) void*)(p))

__device__ __forceinline__ void gload16(const void* g, void* l) {
  __builtin_amdgcn_global_load_lds(AS1(g), AS3(l), 16, 0, 0);
}

__device__ __forceinline__ float sgm(float x) {
  // sigmoid(16*x) = 1/(1+2^(-16*log2e*x))
  return __builtin_amdgcn_rcpf(1.0f + __builtin_amdgcn_exp2f(x * -23.083120654223414f));
}

__device__ __forceinline__ unsigned pack2(float a, float b) {
  union { f16 h[2]; unsigned u; } x;
  x.h[0] = (f16)a; x.h[1] = (f16)b;
  return x.u;
}

// ---------------------------------------------------------------------------
// Tiled transpose + f32->f16 convert body: 64x64 tile.
// ---------------------------------------------------------------------------
__device__ __forceinline__ void tbody(const float* __restrict__ ip,
                                      f16* __restrict__ op,
                                      long in_rs, long out_rs) {
  __shared__ float t[64][68];
  int tid = threadIdx.x;
  {
    int c4 = (tid & 15) * 4, r0 = tid >> 4;
#pragma unroll
    for (int p = 0; p < 4; ++p) {
      int r = r0 + 16 * p;
      float4 v = *(const float4*)(ip + (long)r * in_rs + c4);
      t[c4 + 0][r] = v.x; t[c4 + 1][r] = v.y; t[c4 + 2][r] = v.z; t[c4 + 3][r] = v.w;
    }
  }
  __syncthreads();
  {
    int r4 = (tid & 15) * 4, c0 = tid >> 4;
#pragma unroll
    for (int p = 0; p < 4; ++p) {
      int c = c0 + 16 * p;
      float4 v = *(const float4*)(&t[c][r4]);
      union { f16 h[4]; unsigned long long u; } pk;
      pk.h[0] = (f16)v.x; pk.h[1] = (f16)v.y; pk.h[2] = (f16)v.z; pk.h[3] = (f16)v.w;
      *(unsigned long long*)(op + (long)c * out_rs + r4) = pk.u;
    }
  }
}

// inputs: z<4 -> q batch z; z>=4 -> kv batch z-4. (b,f,s)->(b,s,f). grid (16,4,8)
__global__ __launch_bounds__(256) void tin(const float* __restrict__ qin,
                                           const float* __restrict__ kvin,
                                           f16* __restrict__ Xq, f16* __restrict__ Xkv) {
  int z = blockIdx.z;
  const float* in = (z < 4) ? qin : kvin;
  f16* out = (z < 4) ? Xq : Xkv;
  long b = z & 3;
  tbody(in + b * 262144 + (long)(blockIdx.y * 64) * 1024 + blockIdx.x * 64,
        out + b * 262144 + (long)(blockIdx.x * 64) * 256 + blockIdx.y * 64,
        1024, 256);
}

// weights Wq/Wk/Wv: (256,2048) -> (2048,256). grid (32,4,3)
__global__ __launch_bounds__(256) void tw3(const float* __restrict__ Wq,
                                           const float* __restrict__ Wk,
                                           const float* __restrict__ Wv,
                                           f16* __restrict__ Wqt, f16* __restrict__ Wkt,
                                           f16* __restrict__ Wvt) {
  int z = blockIdx.z;
  const float* in = (z == 0) ? Wq : (z == 1) ? Wk : Wv;
  f16* out = (z == 0) ? Wqt : (z == 1) ? Wkt : Wvt;
  tbody(in + (long)(blockIdx.y * 64) * 2048 + blockIdx.x * 64,
        out + (long)(blockIdx.x * 64) * 256 + blockIdx.y * 64,
        2048, 256);
}

// Wz (2048,256) k'=fi*8+h -> Wzt[fo][h*256+fi]. grid (4,4,8), z=h
__global__ __launch_bounds__(256) void twz(const float* __restrict__ Wz,
                                           f16* __restrict__ Wzt) {
  long z = blockIdx.z;
  tbody(Wz + z * 256 + (long)(blockIdx.y * 64) * 2048 + blockIdx.x * 64,
        Wzt + z * 256 + (long)(blockIdx.x * 64) * 2048 + blockIdx.y * 64,
        2048, 2048);
}

// ---------------------------------------------------------------------------
// QKV projection, double-buffered staging. BM=BN=128, BK=64.
// z=0: Q -> Qh[b][h][s][fi]; z=1: K -> Kh; z=2: V -> Vt[b][h][fi][s]
// grid (32,16,3), 256 threads.
// ---------------------------------------------------------------------------
__global__ __launch_bounds__(256) void projk(
    const f16* __restrict__ Xq, const f16* __restrict__ Xkv,
    const f16* __restrict__ Wqt, const f16* __restrict__ Wkt, const f16* __restrict__ Wvt,
    f16* __restrict__ Qh, f16* __restrict__ Kh, f16* __restrict__ Vt) {
  __shared__ char sm[65536];  // 2 x (16KB A + 16KB B); epilogue bounce reuses
  int z = blockIdx.z;
  const f16* A = (z == 0) ? Xq : Xkv;
  const f16* B = (z == 0) ? Wqt : (z == 1) ? Wkt : Wvt;
  int m0 = blockIdx.x * 128, n0 = blockIdx.y * 128;
  int tid = threadIdx.x, wave = tid >> 6, lane = tid & 63;
  int wm = wave & 1, wn = wave >> 1;
  f32x4 acc[4][4];
#pragma unroll
  for (int i = 0; i < 4; ++i)
#pragma unroll
    for (int j = 0; j < 4; ++j) acc[i][j] = (f32x4){0.f, 0.f, 0.f, 0.f};

  auto PSTAGE = [&](int buf, int kt) {
    char* As = sm + buf * 32768;
    char* Bs = As + 16384;
    int k0 = kt * 64;
#pragma unroll
    for (int is = 0; is < 4; ++is) {
      int loff = is * 4096 + wave * 1024;
      int g = loff + lane * 16;
      int row = g >> 7, sl = (g >> 4) & 7;
      int sp = (sl ^ (row & 7)) * 8;
      gload16(A + (long)(m0 + row) * 256 + k0 + sp, As + loff);
      gload16(B + (long)(n0 + row) * 256 + k0 + sp, Bs + loff);
    }
  };

  PSTAGE(0, 0);
  __syncthreads();
  for (int kt = 0; kt < 4; ++kt) {
    int cur = kt & 1;
    if (kt < 3) PSTAGE(cur ^ 1, kt + 1);
    const char* As = sm + cur * 32768;
    const char* Bs = As + 16384;
#pragma unroll
    for (int t = 0; t < 2; ++t) {
      f16x8 af[4], bf[4];
#pragma unroll
      for (int mi = 0; mi < 4; ++mi) {
        int row = wm * 64 + mi * 16 + (lane & 15);
        int sl = (t * 4 + (lane >> 4)) ^ (row & 7);
        af[mi] = *(const f16x8*)(As + row * 128 + sl * 16);
      }
#pragma unroll
      for (int ni = 0; ni < 4; ++ni) {
        int row = wn * 64 + ni * 16 + (lane & 15);
        int sl = (t * 4 + (lane >> 4)) ^ (row & 7);
        bf[ni] = *(const f16x8*)(Bs + row * 128 + sl * 16);
      }
#pragma unroll
      for (int mi = 0; mi < 4; ++mi)
#pragma unroll
        for (int ni = 0; ni < 4; ++ni)
          acc[mi][ni] = __builtin_amdgcn_mfma_f32_16x16x32_f16(af[mi], bf[ni], acc[mi][ni], 0, 0, 0);
    }
    __syncthreads();
  }
  // bounce tile into LDS as L[cc][rs], row stride 272B
#pragma unroll
  for (int mi = 0; mi < 4; ++mi)
#pragma unroll
    for (int ni = 0; ni < 4; ++ni) {
      int cc = wn * 64 + ni * 16 + (lane & 15);
      int rs0 = wm * 64 + mi * 16 + (lane >> 4) * 4;
      union { f16 h[4]; unsigned long long u; } pk;
#pragma unroll
      for (int r = 0; r < 4; ++r) pk.h[r] = (f16)acc[mi][ni][r];
      *(unsigned long long*)(sm + cc * 272 + rs0 * 2) = pk.u;
    }
  __syncthreads();
  if (z < 2) {
    f16* outp = (z == 0) ? Qh : Kh;
#pragma unroll
    for (int pass = 0; pass < 4; ++pass) {
      int item = pass * 256 + tid;
      int rs = item & 127, h = item >> 7;
      int m = m0 + rs, b = m >> 10, s = m & 1023;
      union { unsigned short u16[16]; uint4 q[2]; } pk;
#pragma unroll
      for (int u = 0; u < 16; ++u)
        pk.u16[u] = *(const unsigned short*)(sm + (h + 8 * u) * 272 + rs * 2);
      f16* dst = outp + ((long)(b * 8 + h) * 1024 + s) * 256 + (n0 >> 3);
      *(uint4*)dst = pk.q[0];
      *(uint4*)(dst + 8) = pk.q[1];
    }
  } else {
    int cc = tid >> 1, half = tid & 1;
    int c = n0 + cc, h = c & 7, fi = c >> 3;
    int m = m0 + half * 64;
    int b = m >> 10, s0 = m & 1023;
    uint4 q[8];
#pragma unroll
    for (int j = 0; j < 8; ++j)
      q[j] = *(const uint4*)(sm + cc * 272 + half * 128 + j * 16);
    f16* dst = Vt + ((long)(b * 8 + h) * 256 + fi) * 1024 + s0;
#pragma unroll
    for (int j = 0; j < 8; ++j) *(uint4*)(dst + j * 8) = q[j];
  }
}

// ---------------------------------------------------------------------------
// Fused attention, v2: swapped QK^T (lane-local S rows) + in-register
// sigmoid->f16 pack + permlane redistribute to PV A-fragment (no P LDS),
// double-buffered K/V staging, ONE barrier per j-tile.
// Per block: one (bh, 64-row i-tile); per wave: 16 i-rows x 256 f.
// Zb aliases Qh (Q rows read to regs before Z rows written; disjoint blocks).
// grid 512, 256 threads.
// ---------------------------------------------------------------------------
__global__ __launch_bounds__(256) void attnk(
    const f16* __restrict__ Qh, const f16* __restrict__ Kh,
    const f16* __restrict__ Vt, f16* __restrict__ Zb) {
  __shared__ char sm[65536];  // 2 x (K 16KB + V 16KB); epilogue bounce reuses
  int flat = blockIdx.x;
  int xcd = flat & 7, slotb = flat >> 3;
  int bh = xcd + 8 * (slotb & 3);   // 4 heads per XCD
  int i0 = (slotb >> 2) * 64;
  int tid = threadIdx.x, wave = tid >> 6, lane = tid & 63;
  int l15 = lane & 15, l4 = lane >> 4;
  const f16* Qp = Qh + (long)bh * 262144;
  const f16* Kp = Kh + (long)bh * 262144;
  const f16* Vp = Vt + (long)bh * 262144;
  f16x8 q[8];
  {
    const f16* qr = Qp + (long)(i0 + wave * 16 + l15) * 256 + l4 * 8;
#pragma unroll
    for (int t = 0; t < 8; ++t) q[t] = *(const f16x8*)(qr + t * 32);
  }
  f32x4 acc[16];
#pragma unroll
  for (int i = 0; i < 16; ++i) acc[i] = (f32x4){0.f, 0.f, 0.f, 0.f};

  auto STAGE = [&](int buf, int j0) {
    char* Ks = sm + buf * 32768;
    char* Vs = Ks + 16384;
#pragma unroll
    for (int is = 0; is < 4; ++is) {
      int loff = is * 4096 + wave * 1024;
      int g = loff + lane * 16;
      {
        int row = g >> 9, sl = (g >> 4) & 31;
        gload16(Kp + (long)(j0 + row) * 256 + ((sl ^ (row & 7)) * 8), Ks + loff);
      }
      {
        int row = g >> 6, sl = (g >> 4) & 3;
        gload16(Vp + (long)row * 1024 + j0 + ((sl ^ ((row >> 1) & 3)) * 8), Vs + loff);
      }
    }
  };

  STAGE(0, 0);
  __syncthreads();
  for (int jt = 0; jt < 32; ++jt) {
    int cur = jt & 1;
    if (jt < 31) STAGE(cur ^ 1, (jt + 1) * 32);
    const char* Ks = sm + cur * 32768;
    const char* Vs = Ks + 16384;
    // QK^T swapped: A=K rows j, B=Q cols i  ->  lane holds S[i=l15][8 j's]
    f32x4 s0 = (f32x4){0.f, 0.f, 0.f, 0.f};
    f32x4 s1 = (f32x4){0.f, 0.f, 0.f, 0.f};
#pragma unroll
    for (int t = 0; t < 8; ++t) {
      int sl = (t * 4 + l4) ^ (l15 & 7);
      f16x8 k0 = *(const f16x8*)(Ks + l15 * 512 + sl * 16);
      f16x8 k1 = *(const f16x8*)(Ks + (16 + l15) * 512 + sl * 16);
      s0 = __builtin_amdgcn_mfma_f32_16x16x32_f16(k0, q[t], s0, 0, 0, 0);
      s1 = __builtin_amdgcn_mfma_f32_16x16x32_f16(k1, q[t], s1, 0, 0, 0);
    }
    // sigmoid + pack pairs: lane holds P[i=l15][j] for j in {4*l4..+3} u {16+4*l4..+3}
    unsigned u00 = pack2(sgm(s0[0]), sgm(s0[1]));
    unsigned u01 = pack2(sgm(s0[2]), sgm(s0[3]));
    unsigned u10 = pack2(sgm(s1[0]), sgm(s1[1]));
    unsigned u11 = pack2(sgm(s1[2]), sgm(s1[3]));
    // redistribute: (W0,W2) = pl16swap(pl32swap(u00,u10)); (W1,W3) likewise
    auto a0 = __builtin_amdgcn_permlane32_swap(u00, u10, false, false);
    auto w02 = __builtin_amdgcn_permlane16_swap(a0[0], a0[1], false, false);
    auto a1 = __builtin_amdgcn_permlane32_swap(u01, u11, false, false);
    auto w13 = __builtin_amdgcn_permlane16_swap(a1[0], a1[1], false, false);
    union { unsigned u[4]; f16x8 v; } pa;
    pa.u[0] = w02[0]; pa.u[1] = w13[0]; pa.u[2] = w02[1]; pa.u[3] = w13[1];
    // PV: wave covers its 16 i-rows x all 256 f
#pragma unroll
    for (int nf = 0; nf < 16; ++nf) {
      int fr = nf * 16 + l15;
      int sl = l4 ^ ((fr >> 1) & 3);
      f16x8 vb = *(const f16x8*)(Vs + fr * 64 + sl * 16);
      acc[nf] = __builtin_amdgcn_mfma_f32_16x16x32_f16(pa.v, vb, acc[nf], 0, 0, 0);
    }
    __syncthreads();
  }
  // epilogue: bounce 64x256 f16 through swizzled LDS, coalesced b128 stores
#pragma unroll
  for (int nf = 0; nf < 16; ++nf)
#pragma unroll
    for (int r = 0; r < 4; ++r) {
      int il = wave * 16 + l4 * 4 + r;
      int f = nf * 16 + l15;
      *(f16*)(sm + il * 512 + ((f * 2) ^ (((il >> 2) & 3) << 5))) = (f16)acc[nf][r];
    }
  __syncthreads();
  f16* zp = Zb + ((long)bh * 1024 + i0) * 256;
#pragma unroll
  for (int c = 0; c < 8; ++c) {
    int il = c * 8 + (tid >> 5);
    int fb = (tid & 31) * 16;
    uint4 v = *(const uint4*)(sm + il * 512 + (fb ^ (((il >> 2) & 3) << 5)));
    *(uint4*)((char*)zp + il * 512 + fb) = v;
  }
}

// ---------------------------------------------------------------------------
// Output projection + ReLU, double-buffered. BM=BN=BK=64.
// grid (4,16,4), 256 threads.
// ---------------------------------------------------------------------------
__global__ __launch_bounds__(256) void zkern(
    const f16* __restrict__ Wzt, const f16* __restrict__ Zb,
    float* __restrict__ out) {
  __shared__ char sm[32768];  // 2 x (8KB A + 8KB B)
  int fo0 = blockIdx.x * 64, s0 = blockIdx.y * 64, b = blockIdx.z;
  int tid = threadIdx.x, wave = tid >> 6, lane = tid & 63;
  int wm = wave & 1, wn = wave >> 1;
  f32x4 acc[2][2];
#pragma unroll
  for (int i = 0; i < 2; ++i)
#pragma unroll
    for (int j = 0; j < 2; ++j) acc[i][j] = (f32x4){0.f, 0.f, 0.f, 0.f};

  auto ZSTAGE = [&](int buf, int kt) {
    char* As = sm + buf * 16384;
    char* Bs = As + 8192;
    int k0 = kt * 64, h = k0 >> 8, fi0 = k0 & 255;
#pragma unroll
    for (int is = 0; is < 2; ++is) {
      int loff = is * 4096 + wave * 1024;
      int g = loff + lane * 16;
      int row = g >> 7, sl = (g >> 4) & 7;
      int sp = (sl ^ (row & 7)) * 8;
      gload16(Wzt + (long)(fo0 + row) * 2048 + k0 + sp, As + loff);
      gload16(Zb + ((long)(b * 8 + h) * 1024 + s0 + row) * 256 + fi0 + sp, Bs + loff);
    }
  };

  ZSTAGE(0, 0);
  __syncthreads();
  for (int kt = 0; kt < 32; ++kt) {
    int cur = kt & 1;
    if (kt < 31) ZSTAGE(cur ^ 1, kt + 1);
    const char* As = sm + cur * 16384;
    const char* Bs = As + 8192;
#pragma unroll
    for (int t = 0; t < 2; ++t) {
      f16x8 af[2], bf[2];
#pragma unroll
      for (int mi = 0; mi < 2; ++mi) {
        int row = wm * 32 + mi * 16 + (lane & 15);
        int sl = (t * 4 + (lane >> 4)) ^ (row & 7);
        af[mi] = *(const f16x8*)(As + row * 128 + sl * 16);
      }
#pragma unroll
      for (int ni = 0; ni < 2; ++ni) {
        int row = wn * 32 + ni * 16 + (lane & 15);
        int sl = (t * 4 + (lane >> 4)) ^ (row & 7);
        bf[ni] = *(const f16x8*)(Bs + row * 128 + sl * 16);
      }
#pragma unroll
      for (int mi = 0; mi < 2; ++mi)
#pragma unroll
        for (int ni = 0; ni < 2; ++ni)
          acc[mi][ni] = __builtin_amdgcn_mfma_f32_16x16x32_f16(af[mi], bf[ni], acc[mi][ni], 0, 0, 0);
    }
    __syncthreads();
  }
#pragma unroll
  for (int mi = 0; mi < 2; ++mi)
#pragma unroll
    for (int ni = 0; ni < 2; ++ni)
#pragma unroll
      for (int r = 0; r < 4; ++r) {
        int fo = fo0 + wm * 32 + mi * 16 + (lane >> 4) * 4 + r;
        int s = s0 + wn * 32 + ni * 16 + (lane & 15);
        float v = acc[mi][ni][r];
        out[((long)b * 256 + fo) * 1024 + s] = v > 0.f ? v : 0.f;
      }
}

extern "C" void kernel_launch(void* const* d_in, const int* in_sizes, int n_in,
                              void* d_out, int out_size, void* d_ws, size_t ws_size,
                              hipStream_t stream) {
  const float* qin = (const float*)d_in[0];
  const float* kvin = (const float*)d_in[1];
  const float* Wq = (const float*)d_in[2];
  const float* Wk = (const float*)d_in[3];
  const float* Wv = (const float*)d_in[4];
  const float* Wz = (const float*)d_in[5];
  float* out = (float*)d_out;
  char* ws = (char*)d_ws;
  const long MB = 1 << 20;
  f16* Xq  = (f16*)(ws + 0 * MB);
  f16* Xkv = (f16*)(ws + 2 * MB);
  f16* Wqt = (f16*)(ws + 4 * MB);
  f16* Wkt = (f16*)(ws + 5 * MB);
  f16* Wvt = (f16*)(ws + 6 * MB);
  f16* Wzt = (f16*)(ws + 7 * MB);
  f16* Qh  = (f16*)(ws + 8 * MB);   // 16MB, aliased by Zb
  f16* Kh  = (f16*)(ws + 24 * MB);  // 16MB
  f16* Vt  = (f16*)(ws + 40 * MB);  // 16MB
  f16* Zb  = Qh;
  dim3 blk(256);
  tin<<<dim3(16, 4, 8), blk, 0, stream>>>(qin, kvin, Xq, Xkv);
  tw3<<<dim3(32, 4, 3), blk, 0, stream>>>(Wq, Wk, Wv, Wqt, Wkt, Wvt);
  twz<<<dim3(4, 4, 8), blk, 0, stream>>>(Wz, Wzt);
  projk<<<dim3(32, 16, 3), blk, 0, stream>>>(Xq, Xkv, Wqt, Wkt, Wvt, Qh, Kh, Vt);
  attnk<<<dim3(512), blk, 0, stream>>>(Qh, Kh, Vt, Zb);
  zkern<<<dim3(4, 16, 4), blk, 0, stream>>>(Wzt, Zb, out);
}